// Round 6
// baseline (63.756 us; speedup 1.0000x reference)
//
#include <hip/hip_runtime.h>
#include <hip/hip_bf16.h>

// BQQ dims: P=2, J=32, K=32, M=128, L=16, N=128; B=512; in=kn=4096; out=jm=4096
typedef __attribute__((ext_vector_type(4))) float f32x4;
typedef __attribute__((ext_vector_type(8))) short bf16x8;
typedef __attribute__((ext_vector_type(4))) unsigned int u32x4;

#define GLOBAL_AS __attribute__((address_space(1)))
#define LDS_AS __attribute__((address_space(3)))

static __device__ __forceinline__ unsigned short f2bf(float f) {
  __hip_bfloat16 h = __float2bfloat16(f);
  return __builtin_bit_cast(unsigned short, h);
}
static __device__ __forceinline__ float bf2f(unsigned short u) {
  unsigned int v = ((unsigned int)u) << 16;
  return __builtin_bit_cast(float, v);
}
static __device__ __forceinline__ void load_lds16(const void* g, void* l) {
  __builtin_amdgcn_global_load_lds((GLOBAL_AS void*)g, (LDS_AS void*)l, 16, 0, 0);
}

// ---------------- 1) per-block min/max of input (2M f32), 256 blocks ----------------
__global__ __launch_bounds__(256) void k_minmax_part(const float* __restrict__ x,
                                                     float* __restrict__ part) {
  int tid = blockIdx.x * 256 + threadIdx.x;  // 65536 threads, 8 float4 each
  const float4* xv = (const float4*)x;
  float mn = 3.4e38f, mx = -3.4e38f;
#pragma unroll
  for (int rep = 0; rep < 8; ++rep) {
    float4 v = xv[tid + rep * 65536];
    mn = fminf(mn, fminf(fminf(v.x, v.y), fminf(v.z, v.w)));
    mx = fmaxf(mx, fmaxf(fmaxf(v.x, v.y), fmaxf(v.z, v.w)));
  }
#pragma unroll
  for (int o = 32; o > 0; o >>= 1) {
    mn = fminf(mn, __shfl_down(mn, o));
    mx = fmaxf(mx, __shfl_down(mx, o));
  }
  __shared__ float smn[4], smx[4];
  int lane = threadIdx.x & 63, w = threadIdx.x >> 6;
  if (lane == 0) { smn[w] = mn; smx[w] = mx; }
  __syncthreads();
  if (threadIdx.x == 0) {
    mn = fminf(fminf(smn[0], smn[1]), fminf(smn[2], smn[3]));
    mx = fmaxf(fmaxf(smx[0], smx[1]), fmaxf(smx[2], smx[3]));
    part[2 * blockIdx.x] = mn;
    part[2 * blockIdx.x + 1] = mx;
  }
}

// ---------------- 2) fused: blocks 0..1023 = build W (MFMA); 1024..3071 = quantize ----------------
__global__ __launch_bounds__(256) void k_fused(const float* __restrict__ x,
                                               const float* __restrict__ part,
                                               const float* __restrict__ Ysg,
                                               const float* __restrict__ Zsg,
                                               const float* __restrict__ Ysc,
                                               const float* __restrict__ Zsc,
                                               const float* __restrict__ Acoef,
                                               float* __restrict__ scl,
                                               unsigned short* __restrict__ xq,
                                               unsigned short* __restrict__ W) {
  const int t = threadIdx.x;
  if (blockIdx.x < 1024) {
    // ---- build_w (MFMA) ----
    const int jk = blockIdx.x;  // j*32+k
    __shared__ unsigned short Yb[2 * 128 * 24];  // [p*128+m][24] halves; data in [0..16)
    __shared__ unsigned short Zb[128 * 36];      // [n][36] halves; data pl in [0..32)
    __shared__ float B1p[2][128];                // per-p row sign-sums
    __shared__ float C1[128];
    float cf0[2], cf2[2], cf4[2];
    float Dv;
    {
      float ys0 = Ysc[jk], zs0 = Zsc[jk], ys1 = Ysc[1024 + jk], zs1 = Zsc[1024 + jk];
      const float* A0p = Acoef + (size_t)jk * 4;
      const float* A1p = Acoef + (size_t)(1024 + jk) * 4;
      cf0[0] = A0p[0] * ys0 * zs0; cf0[1] = A1p[0] * ys1 * zs1;
      cf2[0] = A0p[1] * ys0;       cf2[1] = A1p[1] * ys1;
      cf4[0] = A0p[2] * zs0;       cf4[1] = A1p[2] * zs1;
      Dv = A0p[3] + A1p[3];
    }
#pragma unroll
    for (int rep = 0; rep < 4; ++rep) {
      int q = rep * 256 + t;
      int l0 = (q & 3) * 4, m = (q >> 2) & 127, p = q >> 9;
      float4 v = *(const float4*)(Ysg + (size_t)(p * 1024 + jk) * 2048 + m * 16 + l0);
      float s4 = v.x + v.y + v.z + v.w;
      s4 += __shfl_xor(s4, 1);
      s4 += __shfl_xor(s4, 2);
      if ((t & 3) == 0) B1p[p][m] = s4;
      float c0 = cf0[p];
      ushort4 o = make_ushort4(f2bf(c0 * v.x), f2bf(c0 * v.y), f2bf(c0 * v.z), f2bf(c0 * v.w));
      *(ushort4*)&Yb[(p * 128 + m) * 24 + l0] = o;
    }
#pragma unroll
    for (int rep = 0; rep < 4; ++rep) {
      int q = rep * 256 + t;
      int n0 = (q & 31) * 4, l = (q >> 5) & 15, p = q >> 9;
      float4 v = *(const float4*)(Zsg + (size_t)(p * 1024 + jk) * 2048 + l * 128 + n0);
      int pl = p * 16 + l;
      Zb[(n0 + 0) * 36 + pl] = f2bf(v.x);
      Zb[(n0 + 1) * 36 + pl] = f2bf(v.y);
      Zb[(n0 + 2) * 36 + pl] = f2bf(v.z);
      Zb[(n0 + 3) * 36 + pl] = f2bf(v.w);
    }
    __syncthreads();
    if (t < 128) {
      float s0 = 0.f, s1 = 0.f;
#pragma unroll
      for (int l = 0; l < 16; ++l) {
        s0 += bf2f(Zb[t * 36 + l]);
        s1 += bf2f(Zb[t * 36 + 16 + l]);
      }
      C1[t] = cf4[0] * s0 + cf4[1] * s1;
    }
    __syncthreads();
    const int lane = t & 63, wid = t >> 6;
    const int wm = wid >> 1, wn = wid & 1;
    const int grp = lane >> 4;
    bf16x8 af[4], bfr[4];
#pragma unroll
    for (int fm = 0; fm < 4; ++fm) {
      int m = wm * 64 + fm * 16 + (lane & 15);
      af[fm] = *(const bf16x8*)((const char*)Yb + ((grp >> 1) * 128 + m) * 48 + (grp & 1) * 16);
    }
#pragma unroll
    for (int fn = 0; fn < 4; ++fn) {
      int n = wn * 64 + fn * 16 + (lane & 15);
      const char* zp = (const char*)Zb + n * 72 + grp * 16;
      uint2 z0 = *(const uint2*)zp;
      uint2 z1 = *(const uint2*)(zp + 8);
      u32x4 zw; zw[0] = z0.x; zw[1] = z0.y; zw[2] = z1.x; zw[3] = z1.y;
      bfr[fn] = __builtin_bit_cast(bf16x8, zw);
    }
    f32x4 acc[4][4];
#pragma unroll
    for (int fm = 0; fm < 4; ++fm)
#pragma unroll
      for (int fn = 0; fn < 4; ++fn)
        acc[fm][fn] = __builtin_amdgcn_mfma_f32_16x16x32_bf16(af[fm], bfr[fn], (f32x4)(0.f), 0, 0, 0);
    const int j = jk >> 5, k = jk & 31;
    float c1v[4];
#pragma unroll
    for (int fn = 0; fn < 4; ++fn) c1v[fn] = C1[wn * 64 + fn * 16 + (lane & 15)];
#pragma unroll
    for (int fm = 0; fm < 4; ++fm) {
#pragma unroll
      for (int i = 0; i < 4; ++i) {
        int row = wm * 64 + fm * 16 + (grp)*4 + i;
        float b1v = cf2[0] * B1p[0][row] + cf2[1] * B1p[1][row] + Dv;
        size_t rowoff = (size_t)(j * 128 + row) * 4096 + (size_t)(k * 128);
#pragma unroll
        for (int fn = 0; fn < 4; ++fn) {
          int col = wn * 64 + fn * 16 + (lane & 15);
          W[rowoff + col] = f2bf(acc[fm][fn][i] + b1v + c1v[fn]);
        }
      }
    }
  } else {
    // ---- quantize (with in-block redundant scale reduce) ----
    const int qb = blockIdx.x - 1024;
    float2 v2 = ((const float2*)part)[t];  // 256 float2 = 512 partials
    float mn = v2.x, mx = v2.y;
#pragma unroll
    for (int o = 32; o > 0; o >>= 1) {
      mn = fminf(mn, __shfl_down(mn, o));
      mx = fmaxf(mx, __shfl_down(mx, o));
    }
    __shared__ float smn2[4], smx2[4], ssc[1];
    int lane = t & 63, w = t >> 6;
    if (lane == 0) { smn2[w] = mn; smx2[w] = mx; }
    __syncthreads();
    if (t == 0) {
      mn = fminf(fminf(smn2[0], smn2[1]), fminf(smn2[2], smn2[3]));
      mx = fmaxf(fmaxf(smx2[0], smx2[1]), fmaxf(smx2[2], smx2[3]));
      ssc[0] = fmaxf((mx - mn) / 254.0f, 1e-8f);
      if (qb == 0) scl[0] = ssc[0];
    }
    __syncthreads();
    const float s = ssc[0];
    int i = qb * 256 + t;
    float4 v = ((const float4*)x)[i];
    float a = fminf(fmaxf(rintf(v.x / s), -127.f), 127.f);
    float b = fminf(fmaxf(rintf(v.y / s), -127.f), 127.f);
    float c = fminf(fmaxf(rintf(v.z / s), -127.f), 127.f);
    float d = fminf(fmaxf(rintf(v.w / s), -127.f), 127.f);
    ((ushort4*)xq)[i] = make_ushort4(f2bf(a), f2bf(b), f2bf(c), f2bf(d));
  }
}

// ---------------- 3) GEMM split-K8: BM=256,BN=256,BK=64; 8 waves 2x4, wave 128x64 ----------------
// Grid 256 = 2(bm) x 16(bn) x 8(sk); K-slice 512 = 8 iters. LDS 2x64KB dbuf,
// stage-ahead-1, counted vmcnt(8) (8 loads/wave/iter; never 0 in loop).
// XOR swizzle byte^((row&7)<<4) on global source col + on LDS reads.
// sk==0 writes raw f32 acc to out; sk>0 writes bf16 partial to P[sk-1].
__global__ __launch_bounds__(512) void k_gemm(const unsigned short* __restrict__ Xq,
                                              const unsigned short* __restrict__ W,
                                              float* __restrict__ out,
                                              unsigned short* __restrict__ P) {
  __shared__ unsigned short Al[2][256 * 64];  // 2 x 32KB
  __shared__ unsigned short Bl[2][256 * 64];  // 2 x 32KB
  const int t = threadIdx.x, lane = t & 63, wid = t >> 6;  // wid 0..7
  // XCD-chunked bijective swizzle (grid 256 % 8 == 0): XCD x owns wg [32x,32x+32)
  const int wg = (blockIdx.x & 7) * 32 + (blockIdx.x >> 3);
  const int bn = wg >> 4;        // 0..15 (2 bn panels per XCD -> 4MB W/XCD)
  const int sk = (wg >> 1) & 7;  // K slice 0..7
  const int bm = wg & 1;         // 0..1
  const int wm = wid >> 2, wn = wid & 3;  // wave tile 128x64 (2x4 waves)
  const int kbase = sk * 512;
  f32x4 acc[8][4];
#pragma unroll
  for (int a = 0; a < 8; ++a)
#pragma unroll
    for (int b = 0; b < 4; ++b) acc[a][b] = (f32x4)(0.f);

  const int lr = lane >> 3;         // row-in-chunk 0..7
  const int lcb = (lane & 7) * 16;  // byte col in 128B row

  auto STAGE = [&](int buf, int kt) {
    const int k0 = kbase + kt * 64;
    // A tile 256x64: 32 chunks of 1KB, 4 per wave
#pragma unroll
    for (int c = 0; c < 4; ++c) {
      int chunk = wid * 4 + c;
      int r = chunk * 8 + lr;
      int colb = lcb ^ ((r & 7) << 4);
      load_lds16(Xq + ((size_t)(bm * 256 + r) << 12) + k0 + (colb >> 1), &Al[buf][chunk * 512]);
    }
    // B tile 256x64: 32 chunks, 4 per wave
#pragma unroll
    for (int c = 0; c < 4; ++c) {
      int chunk = wid * 4 + c;
      int r = chunk * 8 + lr;
      int colb = lcb ^ ((r & 7) << 4);
      load_lds16(W + ((size_t)(bn * 256 + r) << 12) + k0 + (colb >> 1), &Bl[buf][chunk * 512]);
    }
  };

  auto COMPUTE = [&](int buf) {
#pragma unroll
    for (int ks = 0; ks < 2; ++ks) {
      bf16x8 af[8], bfr[4];
#pragma unroll
      for (int fm = 0; fm < 8; ++fm) {
        int r = wm * 128 + fm * 16 + (lane & 15);
        int colb = (ks * 64 + ((lane >> 4) * 16)) ^ ((r & 7) << 4);
        af[fm] = *(const bf16x8*)((const char*)&Al[buf][0] + r * 128 + colb);
      }
#pragma unroll
      for (int fn = 0; fn < 4; ++fn) {
        int r = wn * 64 + fn * 16 + (lane & 15);
        int colb = (ks * 64 + ((lane >> 4) * 16)) ^ ((r & 7) << 4);
        bfr[fn] = *(const bf16x8*)((const char*)&Bl[buf][0] + r * 128 + colb);
      }
#pragma unroll
      for (int fm = 0; fm < 8; ++fm)
#pragma unroll
        for (int fn = 0; fn < 4; ++fn)
          acc[fm][fn] = __builtin_amdgcn_mfma_f32_16x16x32_bf16(af[fm], bfr[fn], acc[fm][fn], 0, 0, 0);
    }
  };

  STAGE(0, 0);  // prologue: 8 loads/wave outstanding
  for (int it = 0; it < 8; ++it) {
    STAGE((it + 1) & 1, (it + 1) & 7);  // it=7 restages kt=0 into buf0 (dummy, never read)
    __builtin_amdgcn_sched_barrier(0);
    asm volatile("s_waitcnt vmcnt(8)" ::: "memory");  // stage(it) landed; 8 stay in flight
    __builtin_amdgcn_sched_barrier(0);
    __builtin_amdgcn_s_barrier();                     // buf[it&1] ready for all waves
    __builtin_amdgcn_sched_barrier(0);
    COMPUTE(it & 1);
    __builtin_amdgcn_sched_barrier(0);
    __builtin_amdgcn_s_barrier();                     // reads done before buf reuse
  }

  if (sk == 0) {
#pragma unroll
    for (int fn = 0; fn < 4; ++fn) {
      int col = bn * 256 + wn * 64 + fn * 16 + (lane & 15);
#pragma unroll
      for (int fm = 0; fm < 8; ++fm) {
#pragma unroll
        for (int i = 0; i < 4; ++i) {
          int row = bm * 256 + wm * 128 + fm * 16 + (lane >> 4) * 4 + i;
          out[(size_t)row * 4096 + col] = acc[fm][fn][i];
        }
      }
    }
  } else {
    unsigned short* Pk = P + (size_t)(sk - 1) * 2097152;
#pragma unroll
    for (int fn = 0; fn < 4; ++fn) {
      int col = bn * 256 + wn * 64 + fn * 16 + (lane & 15);
#pragma unroll
      for (int fm = 0; fm < 8; ++fm) {
#pragma unroll
        for (int i = 0; i < 4; ++i) {
          int row = bm * 256 + wm * 128 + fm * 16 + (lane >> 4) * 4 + i;
          Pk[(size_t)row * 4096 + col] = f2bf(acc[fm][fn][i]);
        }
      }
    }
  }
}

// ---------------- 4) epilogue: out = (raw + sum of 7 partials) * s + bias ----------------
__global__ __launch_bounds__(256) void k_epi(float* __restrict__ out,
                                             const unsigned short* __restrict__ P,
                                             const float* __restrict__ scl,
                                             const float* __restrict__ bias) {
  int i4 = blockIdx.x * 256 + threadIdx.x;  // 524288 threads, 4 f32 each
  const float s = scl[0];
  float4 r = ((const float4*)out)[i4];
  float4 bv = ((const float4*)bias)[i4 & 1023];
  float sx = r.x, sy = r.y, sz = r.z, sw = r.w;
#pragma unroll
  for (int k = 0; k < 7; ++k) {
    ushort4 p = ((const ushort4*)(P + (size_t)k * 2097152))[i4];
    sx += bf2f(p.x); sy += bf2f(p.y); sz += bf2f(p.z); sw += bf2f(p.w);
  }
  ((float4*)out)[i4] = make_float4(sx * s + bv.x, sy * s + bv.y, sz * s + bv.z, sw * s + bv.w);
}

// ---------------- fallback GEMM (used if ws too small for partials) ----------------
__global__ __launch_bounds__(512) void k_gemm_fb(const unsigned short* __restrict__ Xq,
                                                 const unsigned short* __restrict__ W,
                                                 const float* __restrict__ scl,
                                                 const float* __restrict__ bias,
                                                 float* __restrict__ out) {
  __shared__ unsigned short Al[4][128 * 64];
  __shared__ unsigned short Bl[4][64 * 64];
  const int t = threadIdx.x, lane = t & 63, wid = t >> 6;
  const int wg = (blockIdx.x & 7) * 32 + (blockIdx.x >> 3);
  const int bm = wg & 3;
  const int bn = wg >> 2;
  const int wm = wid >> 1, wn = wid & 1;
  f32x4 acc[2][2];
#pragma unroll
  for (int a = 0; a < 2; ++a)
#pragma unroll
    for (int b = 0; b < 2; ++b) acc[a][b] = (f32x4)(0.f);
  const int lr = lane >> 3;
  const int lcb = (lane & 7) * 16;
  auto STAGE = [&](int buf, int kt) {
    const int k0 = kt * 64;
#pragma unroll
    for (int c = 0; c < 2; ++c) {
      int chunk = wid * 2 + c;
      int r = chunk * 8 + lr;
      int colb = lcb ^ ((r & 7) << 4);
      load_lds16(Xq + ((size_t)(bm * 128 + r) << 12) + k0 + (colb >> 1), &Al[buf][chunk * 512]);
    }
    {
      int r = wid * 8 + lr;
      int colb = lcb ^ ((r & 7) << 4);
      load_lds16(W + ((size_t)(bn * 64 + r) << 12) + k0 + (colb >> 1), &Bl[buf][wid * 512]);
    }
  };
  auto COMPUTE = [&](int buf) {
#pragma unroll
    for (int ks = 0; ks < 2; ++ks) {
      bf16x8 af[2], bfr[2];
#pragma unroll
      for (int fm = 0; fm < 2; ++fm) {
        int r = wm * 32 + fm * 16 + (lane & 15);
        int colb = (ks * 64 + ((lane >> 4) * 16)) ^ ((r & 7) << 4);
        af[fm] = *(const bf16x8*)((const char*)&Al[buf][0] + r * 128 + colb);
      }
#pragma unroll
      for (int fn = 0; fn < 2; ++fn) {
        int r = wn * 32 + fn * 16 + (lane & 15);
        int colb = (ks * 64 + ((lane >> 4) * 16)) ^ ((r & 7) << 4);
        bfr[fn] = *(const bf16x8*)((const char*)&Bl[buf][0] + r * 128 + colb);
      }
#pragma unroll
      for (int fm = 0; fm < 2; ++fm)
#pragma unroll
        for (int fn = 0; fn < 2; ++fn)
          acc[fm][fn] = __builtin_amdgcn_mfma_f32_16x16x32_bf16(af[fm], bfr[fn], acc[fm][fn], 0, 0, 0);
    }
  };
  STAGE(0, 0); STAGE(1, 1); STAGE(2, 2);
  for (int t64 = 0; t64 < 64; ++t64) {
    STAGE((t64 + 3) & 3, (t64 + 3) & 63);
    __builtin_amdgcn_sched_barrier(0);
    asm volatile("s_waitcnt vmcnt(9)" ::: "memory");
    __builtin_amdgcn_sched_barrier(0);
    __builtin_amdgcn_s_barrier();
    __builtin_amdgcn_sched_barrier(0);
    COMPUTE(t64 & 3);
    __builtin_amdgcn_sched_barrier(0);
    __builtin_amdgcn_s_barrier();
  }
  const float s = scl[0];
#pragma unroll
  for (int fn = 0; fn < 2; ++fn) {
    int col = bn * 64 + wn * 32 + fn * 16 + (lane & 15);
    float bv = bias[col];
#pragma unroll
    for (int fm = 0; fm < 2; ++fm) {
#pragma unroll
      for (int i = 0; i < 4; ++i) {
        int row = bm * 128 + wm * 32 + fm * 16 + (lane >> 4) * 4 + i;
        out[(size_t)row * 4096 + col] = acc[fm][fn][i] * s + bv;
      }
    }
  }
}

extern "C" void kernel_launch(void* const* d_in, const int* in_sizes, int n_in,
                              void* d_out, int out_size, void* d_ws, size_t ws_size,
                              hipStream_t stream) {
  const float* x    = (const float*)d_in[0];  // (1,512,4096)
  const float* Ysg  = (const float*)d_in[1];  // (2,32,32,128,16)
  const float* Zsg  = (const float*)d_in[2];  // (2,32,32,16,128)
  const float* Ysc  = (const float*)d_in[3];  // (2,32,32)
  const float* Zsc  = (const float*)d_in[4];  // (2,32,32)
  const float* A    = (const float*)d_in[5];  // (2,32,32,4)
  const float* bias = (const float*)d_in[6];  // (4096,)
  float* out = (float*)d_out;

  char* ws = (char*)d_ws;
  float* scl  = (float*)ws;                  // [0] act_scale
  float* part = (float*)(ws + 256);          // 512 f32 partials
  unsigned short* Xq = (unsigned short*)(ws + 65536);                    // 4MB bf16
  unsigned short* W  = (unsigned short*)(ws + 65536 + (size_t)4194304);  // 32MB bf16
  unsigned short* P  = (unsigned short*)(ws + 65536 + (size_t)4194304 + (size_t)33554432);  // 28MB bf16 partials

  k_minmax_part<<<dim3(256), dim3(256), 0, stream>>>(x, part);
  k_fused<<<dim3(3072), dim3(256), 0, stream>>>(x, part, Ysg, Zsg, Ysc, Zsc, A, scl, Xq, W);
  if (ws_size >= (size_t)65536 + 4194304 + 33554432 + 29360128) {
    k_gemm<<<dim3(256), dim3(512), 0, stream>>>(Xq, W, out, P);
    k_epi<<<dim3(2048), dim3(256), 0, stream>>>(out, P, scl, bias);
  } else {
    k_gemm_fb<<<dim3(256), dim3(512), 0, stream>>>(Xq, W, scl, bias, out);
  }
}

// Round 7
// 63.599 us; speedup vs baseline: 1.0025x; 1.0025x over previous
//
#include <hip/hip_runtime.h>
#include <hip/hip_bf16.h>

// BQQ dims: P=2, J=32, K=32, M=128, L=16, N=128; B=512; in=kn=4096; out=jm=4096
typedef __attribute__((ext_vector_type(4))) float f32x4;
typedef __attribute__((ext_vector_type(8))) short bf16x8;
typedef __attribute__((ext_vector_type(4))) unsigned int u32x4;

#define GLOBAL_AS __attribute__((address_space(1)))
#define LDS_AS __attribute__((address_space(3)))

static __device__ __forceinline__ unsigned short f2bf(float f) {
  __hip_bfloat16 h = __float2bfloat16(f);
  return __builtin_bit_cast(unsigned short, h);
}
static __device__ __forceinline__ float bf2f(unsigned short u) {
  unsigned int v = ((unsigned int)u) << 16;
  return __builtin_bit_cast(float, v);
}
static __device__ __forceinline__ void load_lds16(const void* g, void* l) {
  __builtin_amdgcn_global_load_lds((GLOBAL_AS void*)g, (LDS_AS void*)l, 16, 0, 0);
}

// ---------------- 1) per-block min/max of input (2M f32), 256 blocks ----------------
__global__ __launch_bounds__(256) void k_minmax_part(const float* __restrict__ x,
                                                     float* __restrict__ part) {
  int tid = blockIdx.x * 256 + threadIdx.x;  // 65536 threads, 8 float4 each
  const float4* xv = (const float4*)x;
  float mn = 3.4e38f, mx = -3.4e38f;
#pragma unroll
  for (int rep = 0; rep < 8; ++rep) {
    float4 v = xv[tid + rep * 65536];
    mn = fminf(mn, fminf(fminf(v.x, v.y), fminf(v.z, v.w)));
    mx = fmaxf(mx, fmaxf(fmaxf(v.x, v.y), fmaxf(v.z, v.w)));
  }
#pragma unroll
  for (int o = 32; o > 0; o >>= 1) {
    mn = fminf(mn, __shfl_down(mn, o));
    mx = fmaxf(mx, __shfl_down(mx, o));
  }
  __shared__ float smn[4], smx[4];
  int lane = threadIdx.x & 63, w = threadIdx.x >> 6;
  if (lane == 0) { smn[w] = mn; smx[w] = mx; }
  __syncthreads();
  if (threadIdx.x == 0) {
    mn = fminf(fminf(smn[0], smn[1]), fminf(smn[2], smn[3]));
    mx = fmaxf(fmaxf(smx[0], smx[1]), fmaxf(smx[2], smx[3]));
    part[2 * blockIdx.x] = mn;
    part[2 * blockIdx.x + 1] = mx;
  }
}

// ---------------- 2) fused: blocks 0..1023 = build W (MFMA); 1024..3071 = quantize ----------------
__global__ __launch_bounds__(256) void k_fused(const float* __restrict__ x,
                                               const float* __restrict__ part,
                                               const float* __restrict__ Ysg,
                                               const float* __restrict__ Zsg,
                                               const float* __restrict__ Ysc,
                                               const float* __restrict__ Zsc,
                                               const float* __restrict__ Acoef,
                                               float* __restrict__ scl,
                                               unsigned short* __restrict__ xq,
                                               unsigned short* __restrict__ W) {
  const int t = threadIdx.x;
  if (blockIdx.x < 1024) {
    // ---- build_w (MFMA) ----
    const int jk = blockIdx.x;  // j*32+k
    __shared__ unsigned short Yb[2 * 128 * 24];  // [p*128+m][24] halves; data in [0..16)
    __shared__ unsigned short Zb[128 * 36];      // [n][36] halves; data pl in [0..32)
    __shared__ float B1p[2][128];                // per-p row sign-sums
    __shared__ float C1[128];
    float cf0[2], cf2[2], cf4[2];
    float Dv;
    {
      float ys0 = Ysc[jk], zs0 = Zsc[jk], ys1 = Ysc[1024 + jk], zs1 = Zsc[1024 + jk];
      const float* A0p = Acoef + (size_t)jk * 4;
      const float* A1p = Acoef + (size_t)(1024 + jk) * 4;
      cf0[0] = A0p[0] * ys0 * zs0; cf0[1] = A1p[0] * ys1 * zs1;
      cf2[0] = A0p[1] * ys0;       cf2[1] = A1p[1] * ys1;
      cf4[0] = A0p[2] * zs0;       cf4[1] = A1p[2] * zs1;
      Dv = A0p[3] + A1p[3];
    }
#pragma unroll
    for (int rep = 0; rep < 4; ++rep) {
      int q = rep * 256 + t;
      int l0 = (q & 3) * 4, m = (q >> 2) & 127, p = q >> 9;
      float4 v = *(const float4*)(Ysg + (size_t)(p * 1024 + jk) * 2048 + m * 16 + l0);
      float s4 = v.x + v.y + v.z + v.w;
      s4 += __shfl_xor(s4, 1);
      s4 += __shfl_xor(s4, 2);
      if ((t & 3) == 0) B1p[p][m] = s4;
      float c0 = cf0[p];
      ushort4 o = make_ushort4(f2bf(c0 * v.x), f2bf(c0 * v.y), f2bf(c0 * v.z), f2bf(c0 * v.w));
      *(ushort4*)&Yb[(p * 128 + m) * 24 + l0] = o;
    }
#pragma unroll
    for (int rep = 0; rep < 4; ++rep) {
      int q = rep * 256 + t;
      int n0 = (q & 31) * 4, l = (q >> 5) & 15, p = q >> 9;
      float4 v = *(const float4*)(Zsg + (size_t)(p * 1024 + jk) * 2048 + l * 128 + n0);
      int pl = p * 16 + l;
      Zb[(n0 + 0) * 36 + pl] = f2bf(v.x);
      Zb[(n0 + 1) * 36 + pl] = f2bf(v.y);
      Zb[(n0 + 2) * 36 + pl] = f2bf(v.z);
      Zb[(n0 + 3) * 36 + pl] = f2bf(v.w);
    }
    __syncthreads();
    if (t < 128) {
      float s0 = 0.f, s1 = 0.f;
#pragma unroll
      for (int l = 0; l < 16; ++l) {
        s0 += bf2f(Zb[t * 36 + l]);
        s1 += bf2f(Zb[t * 36 + 16 + l]);
      }
      C1[t] = cf4[0] * s0 + cf4[1] * s1;
    }
    __syncthreads();
    const int lane = t & 63, wid = t >> 6;
    const int wm = wid >> 1, wn = wid & 1;
    const int grp = lane >> 4;
    bf16x8 af[4], bfr[4];
#pragma unroll
    for (int fm = 0; fm < 4; ++fm) {
      int m = wm * 64 + fm * 16 + (lane & 15);
      af[fm] = *(const bf16x8*)((const char*)Yb + ((grp >> 1) * 128 + m) * 48 + (grp & 1) * 16);
    }
#pragma unroll
    for (int fn = 0; fn < 4; ++fn) {
      int n = wn * 64 + fn * 16 + (lane & 15);
      const char* zp = (const char*)Zb + n * 72 + grp * 16;
      uint2 z0 = *(const uint2*)zp;
      uint2 z1 = *(const uint2*)(zp + 8);
      u32x4 zw; zw[0] = z0.x; zw[1] = z0.y; zw[2] = z1.x; zw[3] = z1.y;
      bfr[fn] = __builtin_bit_cast(bf16x8, zw);
    }
    f32x4 acc[4][4];
#pragma unroll
    for (int fm = 0; fm < 4; ++fm)
#pragma unroll
      for (int fn = 0; fn < 4; ++fn)
        acc[fm][fn] = __builtin_amdgcn_mfma_f32_16x16x32_bf16(af[fm], bfr[fn], (f32x4)(0.f), 0, 0, 0);
    const int j = jk >> 5, k = jk & 31;
    float c1v[4];
#pragma unroll
    for (int fn = 0; fn < 4; ++fn) c1v[fn] = C1[wn * 64 + fn * 16 + (lane & 15)];
#pragma unroll
    for (int fm = 0; fm < 4; ++fm) {
#pragma unroll
      for (int i = 0; i < 4; ++i) {
        int row = wm * 64 + fm * 16 + (grp)*4 + i;
        float b1v = cf2[0] * B1p[0][row] + cf2[1] * B1p[1][row] + Dv;
        size_t rowoff = (size_t)(j * 128 + row) * 4096 + (size_t)(k * 128);
#pragma unroll
        for (int fn = 0; fn < 4; ++fn) {
          int col = wn * 64 + fn * 16 + (lane & 15);
          W[rowoff + col] = f2bf(acc[fm][fn][i] + b1v + c1v[fn]);
        }
      }
    }
  } else {
    // ---- quantize (with in-block redundant scale reduce) ----
    const int qb = blockIdx.x - 1024;
    float2 v2 = ((const float2*)part)[t];  // 256 float2 = 512 partials
    float mn = v2.x, mx = v2.y;
#pragma unroll
    for (int o = 32; o > 0; o >>= 1) {
      mn = fminf(mn, __shfl_down(mn, o));
      mx = fmaxf(mx, __shfl_down(mx, o));
    }
    __shared__ float smn2[4], smx2[4], ssc[1];
    int lane = t & 63, w = t >> 6;
    if (lane == 0) { smn2[w] = mn; smx2[w] = mx; }
    __syncthreads();
    if (t == 0) {
      mn = fminf(fminf(smn2[0], smn2[1]), fminf(smn2[2], smn2[3]));
      mx = fmaxf(fmaxf(smx2[0], smx2[1]), fmaxf(smx2[2], smx2[3]));
      ssc[0] = fmaxf((mx - mn) / 254.0f, 1e-8f);
      if (qb == 0) scl[0] = ssc[0];
    }
    __syncthreads();
    const float s = ssc[0];
    int i = qb * 256 + t;
    float4 v = ((const float4*)x)[i];
    float a = fminf(fmaxf(rintf(v.x / s), -127.f), 127.f);
    float b = fminf(fmaxf(rintf(v.y / s), -127.f), 127.f);
    float c = fminf(fmaxf(rintf(v.z / s), -127.f), 127.f);
    float d = fminf(fmaxf(rintf(v.w / s), -127.f), 127.f);
    ((ushort4*)xq)[i] = make_ushort4(f2bf(a), f2bf(b), f2bf(c), f2bf(d));
  }
}

// ---------------- 3) GEMM split-K8: BM=256,BN=256,BK=64; 8 waves 2x4, wave 128x64 ----------------
// __launch_bounds__(512, 2): 2 waves/SIMD min -> VGPR budget 256 (acc[8][4]=128
// + frags + addr fit WITHOUT spill; R6's default cap of 112 spilled acc to
// scratch = +21MB write traffic + 46us). LDS 128KB = 1 block/CU anyway.
__global__ __launch_bounds__(512, 2) void k_gemm(const unsigned short* __restrict__ Xq,
                                                 const unsigned short* __restrict__ W,
                                                 float* __restrict__ out,
                                                 unsigned short* __restrict__ P) {
  __shared__ unsigned short Al[2][256 * 64];  // 2 x 32KB
  __shared__ unsigned short Bl[2][256 * 64];  // 2 x 32KB
  const int t = threadIdx.x, lane = t & 63, wid = t >> 6;  // wid 0..7
  // XCD-chunked bijective swizzle (grid 256 % 8 == 0): XCD x owns wg [32x,32x+32)
  const int wg = (blockIdx.x & 7) * 32 + (blockIdx.x >> 3);
  const int bn = wg >> 4;        // 0..15 (2 bn panels per XCD -> 4MB W/XCD)
  const int sk = (wg >> 1) & 7;  // K slice 0..7
  const int bm = wg & 1;         // 0..1
  const int wm = wid >> 2, wn = wid & 3;  // wave tile 128x64 (2x4 waves)
  const int kbase = sk * 512;
  f32x4 acc[8][4];
#pragma unroll
  for (int a = 0; a < 8; ++a)
#pragma unroll
    for (int b = 0; b < 4; ++b) acc[a][b] = (f32x4)(0.f);

  const int lr = lane >> 3;         // row-in-chunk 0..7
  const int lcb = (lane & 7) * 16;  // byte col in 128B row

  auto STAGE = [&](int buf, int kt) {
    const int k0 = kbase + kt * 64;
    // A tile 256x64: 32 chunks of 1KB, 4 per wave
#pragma unroll
    for (int c = 0; c < 4; ++c) {
      int chunk = wid * 4 + c;
      int r = chunk * 8 + lr;
      int colb = lcb ^ ((r & 7) << 4);
      load_lds16(Xq + ((size_t)(bm * 256 + r) << 12) + k0 + (colb >> 1), &Al[buf][chunk * 512]);
    }
    // B tile 256x64: 32 chunks, 4 per wave
#pragma unroll
    for (int c = 0; c < 4; ++c) {
      int chunk = wid * 4 + c;
      int r = chunk * 8 + lr;
      int colb = lcb ^ ((r & 7) << 4);
      load_lds16(W + ((size_t)(bn * 256 + r) << 12) + k0 + (colb >> 1), &Bl[buf][chunk * 512]);
    }
  };

  auto COMPUTE = [&](int buf) {
#pragma unroll
    for (int ks = 0; ks < 2; ++ks) {
      bf16x8 af[8], bfr[4];
#pragma unroll
      for (int fm = 0; fm < 8; ++fm) {
        int r = wm * 128 + fm * 16 + (lane & 15);
        int colb = (ks * 64 + ((lane >> 4) * 16)) ^ ((r & 7) << 4);
        af[fm] = *(const bf16x8*)((const char*)&Al[buf][0] + r * 128 + colb);
      }
#pragma unroll
      for (int fn = 0; fn < 4; ++fn) {
        int r = wn * 64 + fn * 16 + (lane & 15);
        int colb = (ks * 64 + ((lane >> 4) * 16)) ^ ((r & 7) << 4);
        bfr[fn] = *(const bf16x8*)((const char*)&Bl[buf][0] + r * 128 + colb);
      }
#pragma unroll
      for (int fm = 0; fm < 8; ++fm)
#pragma unroll
        for (int fn = 0; fn < 4; ++fn)
          acc[fm][fn] = __builtin_amdgcn_mfma_f32_16x16x32_bf16(af[fm], bfr[fn], acc[fm][fn], 0, 0, 0);
    }
  };

  STAGE(0, 0);  // prologue: 8 loads/wave outstanding
  for (int it = 0; it < 8; ++it) {
    STAGE((it + 1) & 1, (it + 1) & 7);  // it=7 restages kt=0 into buf0 (dummy, never read)
    __builtin_amdgcn_sched_barrier(0);
    asm volatile("s_waitcnt vmcnt(8)" ::: "memory");  // stage(it) landed; 8 stay in flight
    __builtin_amdgcn_sched_barrier(0);
    __builtin_amdgcn_s_barrier();                     // buf[it&1] ready for all waves
    __builtin_amdgcn_sched_barrier(0);
    COMPUTE(it & 1);
    __builtin_amdgcn_sched_barrier(0);
    __builtin_amdgcn_s_barrier();                     // reads done before buf reuse
  }

  if (sk == 0) {
#pragma unroll
    for (int fn = 0; fn < 4; ++fn) {
      int col = bn * 256 + wn * 64 + fn * 16 + (lane & 15);
#pragma unroll
      for (int fm = 0; fm < 8; ++fm) {
#pragma unroll
        for (int i = 0; i < 4; ++i) {
          int row = bm * 256 + wm * 128 + fm * 16 + (lane >> 4) * 4 + i;
          out[(size_t)row * 4096 + col] = acc[fm][fn][i];
        }
      }
    }
  } else {
    unsigned short* Pk = P + (size_t)(sk - 1) * 2097152;
#pragma unroll
    for (int fn = 0; fn < 4; ++fn) {
      int col = bn * 256 + wn * 64 + fn * 16 + (lane & 15);
#pragma unroll
      for (int fm = 0; fm < 8; ++fm) {
#pragma unroll
        for (int i = 0; i < 4; ++i) {
          int row = bm * 256 + wm * 128 + fm * 16 + (lane >> 4) * 4 + i;
          Pk[(size_t)row * 4096 + col] = f2bf(acc[fm][fn][i]);
        }
      }
    }
  }
}

// ---------------- 4) epilogue: out = (raw + sum of 7 partials) * s + bias ----------------
__global__ __launch_bounds__(256) void k_epi(float* __restrict__ out,
                                             const unsigned short* __restrict__ P,
                                             const float* __restrict__ scl,
                                             const float* __restrict__ bias) {
  int i4 = blockIdx.x * 256 + threadIdx.x;  // 524288 threads, 4 f32 each
  const float s = scl[0];
  float4 r = ((const float4*)out)[i4];
  float4 bv = ((const float4*)bias)[i4 & 1023];
  float sx = r.x, sy = r.y, sz = r.z, sw = r.w;
#pragma unroll
  for (int k = 0; k < 7; ++k) {
    ushort4 p = ((const ushort4*)(P + (size_t)k * 2097152))[i4];
    sx += bf2f(p.x); sy += bf2f(p.y); sz += bf2f(p.z); sw += bf2f(p.w);
  }
  ((float4*)out)[i4] = make_float4(sx * s + bv.x, sy * s + bv.y, sz * s + bv.z, sw * s + bv.w);
}

// ---------------- fallback GEMM (used if ws too small for partials) ----------------
__global__ __launch_bounds__(512) void k_gemm_fb(const unsigned short* __restrict__ Xq,
                                                 const unsigned short* __restrict__ W,
                                                 const float* __restrict__ scl,
                                                 const float* __restrict__ bias,
                                                 float* __restrict__ out) {
  __shared__ unsigned short Al[4][128 * 64];
  __shared__ unsigned short Bl[4][64 * 64];
  const int t = threadIdx.x, lane = t & 63, wid = t >> 6;
  const int wg = (blockIdx.x & 7) * 32 + (blockIdx.x >> 3);
  const int bm = wg & 3;
  const int bn = wg >> 2;
  const int wm = wid >> 1, wn = wid & 1;
  f32x4 acc[2][2];
#pragma unroll
  for (int a = 0; a < 2; ++a)
#pragma unroll
    for (int b = 0; b < 2; ++b) acc[a][b] = (f32x4)(0.f);
  const int lr = lane >> 3;
  const int lcb = (lane & 7) * 16;
  auto STAGE = [&](int buf, int kt) {
    const int k0 = kt * 64;
#pragma unroll
    for (int c = 0; c < 2; ++c) {
      int chunk = wid * 2 + c;
      int r = chunk * 8 + lr;
      int colb = lcb ^ ((r & 7) << 4);
      load_lds16(Xq + ((size_t)(bm * 128 + r) << 12) + k0 + (colb >> 1), &Al[buf][chunk * 512]);
    }
    {
      int r = wid * 8 + lr;
      int colb = lcb ^ ((r & 7) << 4);
      load_lds16(W + ((size_t)(bn * 64 + r) << 12) + k0 + (colb >> 1), &Bl[buf][wid * 512]);
    }
  };
  auto COMPUTE = [&](int buf) {
#pragma unroll
    for (int ks = 0; ks < 2; ++ks) {
      bf16x8 af[2], bfr[2];
#pragma unroll
      for (int fm = 0; fm < 2; ++fm) {
        int r = wm * 32 + fm * 16 + (lane & 15);
        int colb = (ks * 64 + ((lane >> 4) * 16)) ^ ((r & 7) << 4);
        af[fm] = *(const bf16x8*)((const char*)&Al[buf][0] + r * 128 + colb);
      }
#pragma unroll
      for (int fn = 0; fn < 2; ++fn) {
        int r = wn * 32 + fn * 16 + (lane & 15);
        int colb = (ks * 64 + ((lane >> 4) * 16)) ^ ((r & 7) << 4);
        bfr[fn] = *(const bf16x8*)((const char*)&Bl[buf][0] + r * 128 + colb);
      }
#pragma unroll
      for (int fm = 0; fm < 2; ++fm)
#pragma unroll
        for (int fn = 0; fn < 2; ++fn)
          acc[fm][fn] = __builtin_amdgcn_mfma_f32_16x16x32_bf16(af[fm], bfr[fn], acc[fm][fn], 0, 0, 0);
    }
  };
  STAGE(0, 0); STAGE(1, 1); STAGE(2, 2);
  for (int t64 = 0; t64 < 64; ++t64) {
    STAGE((t64 + 3) & 3, (t64 + 3) & 63);
    __builtin_amdgcn_sched_barrier(0);
    asm volatile("s_waitcnt vmcnt(9)" ::: "memory");
    __builtin_amdgcn_sched_barrier(0);
    __builtin_amdgcn_s_barrier();
    __builtin_amdgcn_sched_barrier(0);
    COMPUTE(t64 & 3);
    __builtin_amdgcn_sched_barrier(0);
    __builtin_amdgcn_s_barrier();
  }
  const float s = scl[0];
#pragma unroll
  for (int fn = 0; fn < 2; ++fn) {
    int col = bn * 64 + wn * 32 + fn * 16 + (lane & 15);
    float bv = bias[col];
#pragma unroll
    for (int fm = 0; fm < 2; ++fm) {
#pragma unroll
      for (int i = 0; i < 4; ++i) {
        int row = bm * 128 + wm * 32 + fm * 16 + (lane >> 4) * 4 + i;
        out[(size_t)row * 4096 + col] = acc[fm][fn][i] * s + bv;
      }
    }
  }
}

extern "C" void kernel_launch(void* const* d_in, const int* in_sizes, int n_in,
                              void* d_out, int out_size, void* d_ws, size_t ws_size,
                              hipStream_t stream) {
  const float* x    = (const float*)d_in[0];  // (1,512,4096)
  const float* Ysg  = (const float*)d_in[1];  // (2,32,32,128,16)
  const float* Zsg  = (const float*)d_in[2];  // (2,32,32,16,128)
  const float* Ysc  = (const float*)d_in[3];  // (2,32,32)
  const float* Zsc  = (const float*)d_in[4];  // (2,32,32)
  const float* A    = (const float*)d_in[5];  // (2,32,32,4)
  const float* bias = (const float*)d_in[6];  // (4096,)
  float* out = (float*)d_out;

  char* ws = (char*)d_ws;
  float* scl  = (float*)ws;                  // [0] act_scale
  float* part = (float*)(ws + 256);          // 512 f32 partials
  unsigned short* Xq = (unsigned short*)(ws + 65536);                    // 4MB bf16
  unsigned short* W  = (unsigned short*)(ws + 65536 + (size_t)4194304);  // 32MB bf16
  unsigned short* P  = (unsigned short*)(ws + 65536 + (size_t)4194304 + (size_t)33554432);  // 28MB bf16 partials

  k_minmax_part<<<dim3(256), dim3(256), 0, stream>>>(x, part);
  k_fused<<<dim3(3072), dim3(256), 0, stream>>>(x, part, Ysg, Zsg, Ysc, Zsc, A, scl, Xq, W);
  if (ws_size >= (size_t)65536 + 4194304 + 33554432 + 29360128) {
    k_gemm<<<dim3(256), dim3(512), 0, stream>>>(Xq, W, out, P);
    k_epi<<<dim3(2048), dim3(256), 0, stream>>>(out, P, scl, bias);
  } else {
    k_gemm_fb<<<dim3(256), dim3(512), 0, stream>>>(Xq, W, scl, bias, out);
  }
}

// Round 8
// 61.316 us; speedup vs baseline: 1.0398x; 1.0372x over previous
//
#include <hip/hip_runtime.h>
#include <hip/hip_bf16.h>

// BQQ dims: P=2, J=32, K=32, M=128, L=16, N=128; B=512; in=kn=4096; out=jm=4096
typedef __attribute__((ext_vector_type(4))) float f32x4;
typedef __attribute__((ext_vector_type(8))) short bf16x8;
typedef __attribute__((ext_vector_type(4))) unsigned int u32x4;

#define GLOBAL_AS __attribute__((address_space(1)))
#define LDS_AS __attribute__((address_space(3)))

static __device__ __forceinline__ unsigned short f2bf(float f) {
  __hip_bfloat16 h = __float2bfloat16(f);
  return __builtin_bit_cast(unsigned short, h);
}
static __device__ __forceinline__ float bf2f(unsigned short u) {
  unsigned int v = ((unsigned int)u) << 16;
  return __builtin_bit_cast(float, v);
}
static __device__ __forceinline__ void load_lds16(const void* g, void* l) {
  __builtin_amdgcn_global_load_lds((GLOBAL_AS void*)g, (LDS_AS void*)l, 16, 0, 0);
}

// ---------------- 1) per-block min/max of input (2M f32), 256 blocks ----------------
__global__ __launch_bounds__(256) void k_minmax_part(const float* __restrict__ x,
                                                     float* __restrict__ part) {
  int tid = blockIdx.x * 256 + threadIdx.x;  // 65536 threads, 8 float4 each
  const float4* xv = (const float4*)x;
  float mn = 3.4e38f, mx = -3.4e38f;
#pragma unroll
  for (int rep = 0; rep < 8; ++rep) {
    float4 v = xv[tid + rep * 65536];
    mn = fminf(mn, fminf(fminf(v.x, v.y), fminf(v.z, v.w)));
    mx = fmaxf(mx, fmaxf(fmaxf(v.x, v.y), fmaxf(v.z, v.w)));
  }
#pragma unroll
  for (int o = 32; o > 0; o >>= 1) {
    mn = fminf(mn, __shfl_down(mn, o));
    mx = fmaxf(mx, __shfl_down(mx, o));
  }
  __shared__ float smn[4], smx[4];
  int lane = threadIdx.x & 63, w = threadIdx.x >> 6;
  if (lane == 0) { smn[w] = mn; smx[w] = mx; }
  __syncthreads();
  if (threadIdx.x == 0) {
    mn = fminf(fminf(smn[0], smn[1]), fminf(smn[2], smn[3]));
    mx = fmaxf(fmaxf(smx[0], smx[1]), fmaxf(smx[2], smx[3]));
    part[2 * blockIdx.x] = mn;
    part[2 * blockIdx.x + 1] = mx;
  }
}

// ---------------- 2) fused: blocks 0..1023 = build W (MFMA); 1024..3071 = quantize ----------------
__global__ __launch_bounds__(256) void k_fused(const float* __restrict__ x,
                                               const float* __restrict__ part,
                                               const float* __restrict__ Ysg,
                                               const float* __restrict__ Zsg,
                                               const float* __restrict__ Ysc,
                                               const float* __restrict__ Zsc,
                                               const float* __restrict__ Acoef,
                                               float* __restrict__ scl,
                                               unsigned short* __restrict__ xq,
                                               unsigned short* __restrict__ W) {
  const int t = threadIdx.x;
  if (blockIdx.x < 1024) {
    // ---- build_w (MFMA) ----
    const int jk = blockIdx.x;  // j*32+k
    __shared__ unsigned short Yb[2 * 128 * 24];  // [p*128+m][24] halves; data in [0..16)
    __shared__ unsigned short Zb[128 * 36];      // [n][36] halves; data pl in [0..32)
    __shared__ float B1p[2][128];                // per-p row sign-sums
    __shared__ float C1[128];
    float cf0[2], cf2[2], cf4[2];
    float Dv;
    {
      float ys0 = Ysc[jk], zs0 = Zsc[jk], ys1 = Ysc[1024 + jk], zs1 = Zsc[1024 + jk];
      const float* A0p = Acoef + (size_t)jk * 4;
      const float* A1p = Acoef + (size_t)(1024 + jk) * 4;
      cf0[0] = A0p[0] * ys0 * zs0; cf0[1] = A1p[0] * ys1 * zs1;
      cf2[0] = A0p[1] * ys0;       cf2[1] = A1p[1] * ys1;
      cf4[0] = A0p[2] * zs0;       cf4[1] = A1p[2] * zs1;
      Dv = A0p[3] + A1p[3];
    }
#pragma unroll
    for (int rep = 0; rep < 4; ++rep) {
      int q = rep * 256 + t;
      int l0 = (q & 3) * 4, m = (q >> 2) & 127, p = q >> 9;
      float4 v = *(const float4*)(Ysg + (size_t)(p * 1024 + jk) * 2048 + m * 16 + l0);
      float s4 = v.x + v.y + v.z + v.w;
      s4 += __shfl_xor(s4, 1);
      s4 += __shfl_xor(s4, 2);
      if ((t & 3) == 0) B1p[p][m] = s4;
      float c0 = cf0[p];
      ushort4 o = make_ushort4(f2bf(c0 * v.x), f2bf(c0 * v.y), f2bf(c0 * v.z), f2bf(c0 * v.w));
      *(ushort4*)&Yb[(p * 128 + m) * 24 + l0] = o;
    }
#pragma unroll
    for (int rep = 0; rep < 4; ++rep) {
      int q = rep * 256 + t;
      int n0 = (q & 31) * 4, l = (q >> 5) & 15, p = q >> 9;
      float4 v = *(const float4*)(Zsg + (size_t)(p * 1024 + jk) * 2048 + l * 128 + n0);
      int pl = p * 16 + l;
      Zb[(n0 + 0) * 36 + pl] = f2bf(v.x);
      Zb[(n0 + 1) * 36 + pl] = f2bf(v.y);
      Zb[(n0 + 2) * 36 + pl] = f2bf(v.z);
      Zb[(n0 + 3) * 36 + pl] = f2bf(v.w);
    }
    __syncthreads();
    if (t < 128) {
      float s0 = 0.f, s1 = 0.f;
#pragma unroll
      for (int l = 0; l < 16; ++l) {
        s0 += bf2f(Zb[t * 36 + l]);
        s1 += bf2f(Zb[t * 36 + 16 + l]);
      }
      C1[t] = cf4[0] * s0 + cf4[1] * s1;
    }
    __syncthreads();
    const int lane = t & 63, wid = t >> 6;
    const int wm = wid >> 1, wn = wid & 1;
    const int grp = lane >> 4;
    bf16x8 af[4], bfr[4];
#pragma unroll
    for (int fm = 0; fm < 4; ++fm) {
      int m = wm * 64 + fm * 16 + (lane & 15);
      af[fm] = *(const bf16x8*)((const char*)Yb + ((grp >> 1) * 128 + m) * 48 + (grp & 1) * 16);
    }
#pragma unroll
    for (int fn = 0; fn < 4; ++fn) {
      int n = wn * 64 + fn * 16 + (lane & 15);
      const char* zp = (const char*)Zb + n * 72 + grp * 16;
      uint2 z0 = *(const uint2*)zp;
      uint2 z1 = *(const uint2*)(zp + 8);
      u32x4 zw; zw[0] = z0.x; zw[1] = z0.y; zw[2] = z1.x; zw[3] = z1.y;
      bfr[fn] = __builtin_bit_cast(bf16x8, zw);
    }
    f32x4 acc[4][4];
#pragma unroll
    for (int fm = 0; fm < 4; ++fm)
#pragma unroll
      for (int fn = 0; fn < 4; ++fn)
        acc[fm][fn] = __builtin_amdgcn_mfma_f32_16x16x32_bf16(af[fm], bfr[fn], (f32x4)(0.f), 0, 0, 0);
    const int j = jk >> 5, k = jk & 31;
    float c1v[4];
#pragma unroll
    for (int fn = 0; fn < 4; ++fn) c1v[fn] = C1[wn * 64 + fn * 16 + (lane & 15)];
#pragma unroll
    for (int fm = 0; fm < 4; ++fm) {
#pragma unroll
      for (int i = 0; i < 4; ++i) {
        int row = wm * 64 + fm * 16 + (grp)*4 + i;
        float b1v = cf2[0] * B1p[0][row] + cf2[1] * B1p[1][row] + Dv;
        size_t rowoff = (size_t)(j * 128 + row) * 4096 + (size_t)(k * 128);
#pragma unroll
        for (int fn = 0; fn < 4; ++fn) {
          int col = wn * 64 + fn * 16 + (lane & 15);
          W[rowoff + col] = f2bf(acc[fm][fn][i] + b1v + c1v[fn]);
        }
      }
    }
  } else {
    // ---- quantize (with in-block redundant scale reduce) ----
    const int qb = blockIdx.x - 1024;
    float2 v2 = ((const float2*)part)[t];  // 256 float2 = 512 partials
    float mn = v2.x, mx = v2.y;
#pragma unroll
    for (int o = 32; o > 0; o >>= 1) {
      mn = fminf(mn, __shfl_down(mn, o));
      mx = fmaxf(mx, __shfl_down(mx, o));
    }
    __shared__ float smn2[4], smx2[4], ssc[1];
    int lane = t & 63, w = t >> 6;
    if (lane == 0) { smn2[w] = mn; smx2[w] = mx; }
    __syncthreads();
    if (t == 0) {
      mn = fminf(fminf(smn2[0], smn2[1]), fminf(smn2[2], smn2[3]));
      mx = fmaxf(fmaxf(smx2[0], smx2[1]), fmaxf(smx2[2], smx2[3]));
      ssc[0] = fmaxf((mx - mn) / 254.0f, 1e-8f);
      if (qb == 0) scl[0] = ssc[0];
    }
    __syncthreads();
    const float s = ssc[0];
    int i = qb * 256 + t;
    float4 v = ((const float4*)x)[i];
    float a = fminf(fmaxf(rintf(v.x / s), -127.f), 127.f);
    float b = fminf(fmaxf(rintf(v.y / s), -127.f), 127.f);
    float c = fminf(fmaxf(rintf(v.z / s), -127.f), 127.f);
    float d = fminf(fmaxf(rintf(v.w / s), -127.f), 127.f);
    ((ushort4*)xq)[i] = make_ushort4(f2bf(a), f2bf(b), f2bf(c), f2bf(d));
  }
}

// ---------------- 3) GEMM split-K8, co-resident: BM=128,BN=128,BK=64 ----------------
// Grid 1024 = 8(sk) x 4(bm) x 32(bn); 4 waves 2x2, wave tile 64x64, acc[4][4].
// SINGLE 32KB LDS buffer + plain __syncthreads (m97 schedule): the latency of the
// vmcnt(0) drain is hidden by ~4 co-resident blocks/CU (R7's 1-block/CU had none).
// XCD-chunked: XCD x gets wg [128x,128x+128) = exactly K-slice x -> its 4MB W panel = its L2.
// sk==0 writes raw f32 to out (normal layout); sk>0 writes bf16 partials in
// REGISTER-NATIVE layout (8B/lane contiguous -> 512B/store, no write amplification).
__global__ __launch_bounds__(256) void k_gemm(const unsigned short* __restrict__ Xq,
                                              const unsigned short* __restrict__ W,
                                              float* __restrict__ out,
                                              unsigned short* __restrict__ P) {
  __shared__ unsigned short Al[128 * 64];  // 16KB
  __shared__ unsigned short Bl[128 * 64];  // 16KB
  const int t = threadIdx.x, lane = t & 63, wid = t >> 6;  // wid 0..3
  const int wg = (blockIdx.x & 7) * 128 + (blockIdx.x >> 3);  // bijective, 1024%8==0
  const int sk = wg >> 7;        // 0..7  (== XCD id)
  const int bm = (wg >> 5) & 3;  // 0..3
  const int bn = wg & 31;        // 0..31
  const int wm = wid >> 1, wn = wid & 1;  // wave tile 64x64
  const int kbase = sk * 512;
  f32x4 acc[4][4];
#pragma unroll
  for (int a = 0; a < 4; ++a)
#pragma unroll
    for (int b = 0; b < 4; ++b) acc[a][b] = (f32x4)(0.f);

  const int lr = lane >> 3;         // row-in-chunk 0..7
  const int lcb = (lane & 7) * 16;  // byte col in 128B row

  for (int kt = 0; kt < 8; ++kt) {
    const int k0 = kbase + kt * 64;
    // stage A (Xq 128x64): 16 chunks of 1KB, 4 per wave
#pragma unroll
    for (int c = 0; c < 4; ++c) {
      int chunk = wid * 4 + c;
      int r = chunk * 8 + lr;
      int colb = lcb ^ ((r & 7) << 4);
      load_lds16(Xq + ((size_t)(bm * 128 + r) << 12) + k0 + (colb >> 1), &Al[chunk * 512]);
    }
    // stage B (W 128x64): 16 chunks, 4 per wave
#pragma unroll
    for (int c = 0; c < 4; ++c) {
      int chunk = wid * 4 + c;
      int r = chunk * 8 + lr;
      int colb = lcb ^ ((r & 7) << 4);
      load_lds16(W + ((size_t)(bn * 128 + r) << 12) + k0 + (colb >> 1), &Bl[chunk * 512]);
    }
    __syncthreads();  // drain vmcnt -> tile ready (hidden by co-resident blocks)
#pragma unroll
    for (int ks = 0; ks < 2; ++ks) {
      bf16x8 af[4], bfr[4];
#pragma unroll
      for (int fm = 0; fm < 4; ++fm) {
        int r = wm * 64 + fm * 16 + (lane & 15);
        int colb = (ks * 64 + ((lane >> 4) * 16)) ^ ((r & 7) << 4);
        af[fm] = *(const bf16x8*)((const char*)Al + r * 128 + colb);
      }
#pragma unroll
      for (int fn = 0; fn < 4; ++fn) {
        int r = wn * 64 + fn * 16 + (lane & 15);
        int colb = (ks * 64 + ((lane >> 4) * 16)) ^ ((r & 7) << 4);
        bfr[fn] = *(const bf16x8*)((const char*)Bl + r * 128 + colb);
      }
#pragma unroll
      for (int fm = 0; fm < 4; ++fm)
#pragma unroll
        for (int fn = 0; fn < 4; ++fn)
          acc[fm][fn] = __builtin_amdgcn_mfma_f32_16x16x32_bf16(af[fm], bfr[fn], acc[fm][fn], 0, 0, 0);
    }
    __syncthreads();  // all reads done before next stage overwrites
  }

  if (sk == 0) {
#pragma unroll
    for (int fn = 0; fn < 4; ++fn) {
      int col = bn * 128 + wn * 64 + fn * 16 + (lane & 15);
#pragma unroll
      for (int fm = 0; fm < 4; ++fm) {
#pragma unroll
        for (int i = 0; i < 4; ++i) {
          int row = bm * 128 + wm * 64 + fm * 16 + (lane >> 4) * 4 + i;
          out[(size_t)row * 4096 + col] = acc[fm][fn][i];
        }
      }
    }
  } else {
    // register-native coalesced partial store: idx = ((blkL*4+wid)*16+fm*4+fn)*64+lane
    unsigned short* Pk = P + (size_t)(sk - 1) * 2097152;
    const int blkL = bm * 32 + bn;  // logical (unswizzled) block id 0..127
#pragma unroll
    for (int fm = 0; fm < 4; ++fm) {
#pragma unroll
      for (int fn = 0; fn < 4; ++fn) {
        int idx = (((blkL * 4 + wid) * 16 + fm * 4 + fn) * 64) + lane;
        ushort4 o = make_ushort4(f2bf(acc[fm][fn][0]), f2bf(acc[fm][fn][1]),
                                 f2bf(acc[fm][fn][2]), f2bf(acc[fm][fn][3]));
        ((ushort4*)Pk)[idx] = o;
      }
    }
  }
}

// ---------------- 4) epilogue: out = (raw + sum of 7 native-layout partials) * s + bias ----------------
__global__ __launch_bounds__(256) void k_epi(float* __restrict__ out,
                                             const unsigned short* __restrict__ P,
                                             const float* __restrict__ scl,
                                             const float* __restrict__ bias) {
  int g = blockIdx.x * 256 + threadIdx.x;  // 524288 threads, 4 elems each
  // invert native index: g = ((blk*4+wave)*16+fm*4+fn)*64+lane
  const int lane = g & 63;
  const int ff = (g >> 6) & 15;
  const int fn = ff & 3, fm = ff >> 2;
  const int wave = (g >> 10) & 3;
  const int blk = g >> 12;  // 0..127
  const int bm = blk >> 5, bn = blk & 31;
  const int wm = wave >> 1, wn = wave & 1;
  const int row0 = bm * 128 + wm * 64 + fm * 16 + ((lane >> 4) << 2);
  const int col = bn * 128 + wn * 64 + fn * 16 + (lane & 15);
  const float s = scl[0];
  const float bv = bias[col];
  float sum[4];
#pragma unroll
  for (int i = 0; i < 4; ++i) sum[i] = out[(size_t)(row0 + i) * 4096 + col];
#pragma unroll
  for (int k = 0; k < 7; ++k) {
    ushort4 p = ((const ushort4*)(P + (size_t)k * 2097152))[g];
    sum[0] += bf2f(p.x); sum[1] += bf2f(p.y); sum[2] += bf2f(p.z); sum[3] += bf2f(p.w);
  }
#pragma unroll
  for (int i = 0; i < 4; ++i) out[(size_t)(row0 + i) * 4096 + col] = sum[i] * s + bv;
}

// ---------------- fallback GEMM (used if ws too small for partials) ----------------
__global__ __launch_bounds__(512) void k_gemm_fb(const unsigned short* __restrict__ Xq,
                                                 const unsigned short* __restrict__ W,
                                                 const float* __restrict__ scl,
                                                 const float* __restrict__ bias,
                                                 float* __restrict__ out) {
  __shared__ unsigned short Al[4][128 * 64];
  __shared__ unsigned short Bl[4][64 * 64];
  const int t = threadIdx.x, lane = t & 63, wid = t >> 6;
  const int wg = (blockIdx.x & 7) * 32 + (blockIdx.x >> 3);
  const int bm = wg & 3;
  const int bn = wg >> 2;
  const int wm = wid >> 1, wn = wid & 1;
  f32x4 acc[2][2];
#pragma unroll
  for (int a = 0; a < 2; ++a)
#pragma unroll
    for (int b = 0; b < 2; ++b) acc[a][b] = (f32x4)(0.f);
  const int lr = lane >> 3;
  const int lcb = (lane & 7) * 16;
  auto STAGE = [&](int buf, int kt) {
    const int k0 = kt * 64;
#pragma unroll
    for (int c = 0; c < 2; ++c) {
      int chunk = wid * 2 + c;
      int r = chunk * 8 + lr;
      int colb = lcb ^ ((r & 7) << 4);
      load_lds16(Xq + ((size_t)(bm * 128 + r) << 12) + k0 + (colb >> 1), &Al[buf][chunk * 512]);
    }
    {
      int r = wid * 8 + lr;
      int colb = lcb ^ ((r & 7) << 4);
      load_lds16(W + ((size_t)(bn * 64 + r) << 12) + k0 + (colb >> 1), &Bl[buf][wid * 512]);
    }
  };
  auto COMPUTE = [&](int buf) {
#pragma unroll
    for (int ks = 0; ks < 2; ++ks) {
      bf16x8 af[2], bfr[2];
#pragma unroll
      for (int fm = 0; fm < 2; ++fm) {
        int r = wm * 32 + fm * 16 + (lane & 15);
        int colb = (ks * 64 + ((lane >> 4) * 16)) ^ ((r & 7) << 4);
        af[fm] = *(const bf16x8*)((const char*)&Al[buf][0] + r * 128 + colb);
      }
#pragma unroll
      for (int fn = 0; fn < 2; ++fn) {
        int r = wn * 32 + fn * 16 + (lane & 15);
        int colb = (ks * 64 + ((lane >> 4) * 16)) ^ ((r & 7) << 4);
        bfr[fn] = *(const bf16x8*)((const char*)&Bl[buf][0] + r * 128 + colb);
      }
#pragma unroll
      for (int fm = 0; fm < 2; ++fm)
#pragma unroll
        for (int fn = 0; fn < 2; ++fn)
          acc[fm][fn] = __builtin_amdgcn_mfma_f32_16x16x32_bf16(af[fm], bfr[fn], acc[fm][fn], 0, 0, 0);
    }
  };
  STAGE(0, 0); STAGE(1, 1); STAGE(2, 2);
  for (int t64 = 0; t64 < 64; ++t64) {
    STAGE((t64 + 3) & 3, (t64 + 3) & 63);
    __builtin_amdgcn_sched_barrier(0);
    asm volatile("s_waitcnt vmcnt(9)" ::: "memory");
    __builtin_amdgcn_sched_barrier(0);
    __builtin_amdgcn_s_barrier();
    __builtin_amdgcn_sched_barrier(0);
    COMPUTE(t64 & 3);
    __builtin_amdgcn_sched_barrier(0);
    __builtin_amdgcn_s_barrier();
  }
  const float s = scl[0];
#pragma unroll
  for (int fn = 0; fn < 2; ++fn) {
    int col = bn * 64 + wn * 32 + fn * 16 + (lane & 15);
    float bv = bias[col];
#pragma unroll
    for (int fm = 0; fm < 2; ++fm) {
#pragma unroll
      for (int i = 0; i < 4; ++i) {
        int row = bm * 128 + wm * 32 + fm * 16 + (lane >> 4) * 4 + i;
        out[(size_t)row * 4096 + col] = acc[fm][fn][i] * s + bv;
      }
    }
  }
}

extern "C" void kernel_launch(void* const* d_in, const int* in_sizes, int n_in,
                              void* d_out, int out_size, void* d_ws, size_t ws_size,
                              hipStream_t stream) {
  const float* x    = (const float*)d_in[0];  // (1,512,4096)
  const float* Ysg  = (const float*)d_in[1];  // (2,32,32,128,16)
  const float* Zsg  = (const float*)d_in[2];  // (2,32,32,16,128)
  const float* Ysc  = (const float*)d_in[3];  // (2,32,32)
  const float* Zsc  = (const float*)d_in[4];  // (2,32,32)
  const float* A    = (const float*)d_in[5];  // (2,32,32,4)
  const float* bias = (const float*)d_in[6];  // (4096,)
  float* out = (float*)d_out;

  char* ws = (char*)d_ws;
  float* scl  = (float*)ws;                  // [0] act_scale
  float* part = (float*)(ws + 256);          // 512 f32 partials
  unsigned short* Xq = (unsigned short*)(ws + 65536);                    // 4MB bf16
  unsigned short* W  = (unsigned short*)(ws + 65536 + (size_t)4194304);  // 32MB bf16
  unsigned short* P  = (unsigned short*)(ws + 65536 + (size_t)4194304 + (size_t)33554432);  // 28MB bf16 partials

  k_minmax_part<<<dim3(256), dim3(256), 0, stream>>>(x, part);
  k_fused<<<dim3(3072), dim3(256), 0, stream>>>(x, part, Ysg, Zsg, Ysc, Zsc, A, scl, Xq, W);
  if (ws_size >= (size_t)65536 + 4194304 + 33554432 + 29360128) {
    k_gemm<<<dim3(1024), dim3(256), 0, stream>>>(Xq, W, out, P);
    k_epi<<<dim3(2048), dim3(256), 0, stream>>>(out, P, scl, bias);
  } else {
    k_gemm_fb<<<dim3(256), dim3(512), 0, stream>>>(Xq, W, scl, bias, out);
  }
}